// Round 3
// baseline (1626.497 us; speedup 1.0000x reference)
//
#include <hip/hip_runtime.h>
#include <math.h>

#define DEV __device__ __forceinline__

typedef __attribute__((ext_vector_type(4))) float f32x4;
typedef __attribute__((ext_vector_type(8))) __bf16 bf16x8;
typedef __attribute__((ext_vector_type(4))) unsigned short u16x4;
typedef __attribute__((ext_vector_type(8))) unsigned short u16x8;

// ---------- constants ----------
enum {
  LAYERS = 6, NH = 12, DM = 768, FFD = 3072, BB = 4, NT = 1024,
  MM = BB * NT,          // 4096 token rows
  TD = 3 * DM            // 2304
};

// ---------- helpers ----------
DEV unsigned short f2bf(float f) {
  union { float f; unsigned u; } c; c.f = f;
  unsigned u = c.u;
  return (unsigned short)((u + 0x7fffu + ((u >> 16) & 1u)) >> 16);
}

DEV void gll16(const void* gsrc, void* ldst) {
  __builtin_amdgcn_global_load_lds(
      (const __attribute__((address_space(1))) unsigned int*)gsrc,
      (__attribute__((address_space(3))) unsigned int*)ldst, 16, 0, 0);
}

DEV f32x4 mfma16(bf16x8 a, bf16x8 b, f32x4 c) {
  return __builtin_amdgcn_mfma_f32_16x16x32_bf16(a, b, c, 0, 0, 0);
}

// ---------- fp32 -> bf16 weight convert ----------
__global__ __launch_bounds__(256) void cvt_kernel(const f32x4* __restrict__ in,
                                                  u16x4* __restrict__ out, int n4) {
  int i = blockIdx.x * blockDim.x + threadIdx.x;
  int stride = gridDim.x * blockDim.x;
  for (; i < n4; i += stride) {
    f32x4 v = in[i];
    u16x4 o;
    o[0] = f2bf(v[0]); o[1] = f2bf(v[1]); o[2] = f2bf(v[2]); o[3] = f2bf(v[3]);
    out[i] = o;
  }
}

// ---------- LayerNorm (optionally fused residual add), wave per row ----------
// out paths: xout (fp32, may alias xin) and/or bfout (bf16)
__global__ __launch_bounds__(256) void ln_kernel(const float* __restrict__ xin,
                                                 const float* __restrict__ ain,
                                                 const float* __restrict__ gam,
                                                 const float* __restrict__ bet,
                                                 float* __restrict__ xout,
                                                 unsigned short* __restrict__ bfout) {
  const int row  = blockIdx.x * 4 + (threadIdx.x >> 6);
  const int lane = threadIdx.x & 63;
  const f32x4* xr = (const f32x4*)(xin + (size_t)row * DM);
  f32x4 v[3];
#pragma unroll
  for (int p = 0; p < 3; p++) v[p] = xr[lane + 64 * p];
  if (ain) {
    const f32x4* ar = (const f32x4*)(ain + (size_t)row * DM);
#pragma unroll
    for (int p = 0; p < 3; p++) v[p] += ar[lane + 64 * p];
  }
  float s = 0.f, sq = 0.f;
#pragma unroll
  for (int p = 0; p < 3; p++)
#pragma unroll
    for (int j = 0; j < 4; j++) { float f = v[p][j]; s += f; sq += f * f; }
#pragma unroll
  for (int o = 1; o < 64; o <<= 1) {
    s  += __shfl_xor(s, o, 64);
    sq += __shfl_xor(sq, o, 64);
  }
  const float mean = s * (1.0f / DM);
  const float var  = sq * (1.0f / DM) - mean * mean;
  const float rstd = rsqrtf(var + 1e-5f);
  const f32x4* gr = (const f32x4*)gam;
  const f32x4* br = (const f32x4*)bet;
#pragma unroll
  for (int p = 0; p < 3; p++) {
    f32x4 gv = gr[lane + 64 * p];
    f32x4 bv = br[lane + 64 * p];
    f32x4 o = (v[p] - mean) * rstd * gv + bv;
    if (xout) ((f32x4*)(xout + (size_t)row * DM))[lane + 64 * p] = o;
    if (bfout) {
      u16x4 h;
      h[0] = f2bf(o[0]); h[1] = f2bf(o[1]); h[2] = f2bf(o[2]); h[3] = f2bf(o[3]);
      ((u16x4*)(bfout + (size_t)row * DM))[lane + 64 * p] = h;
    }
  }
}

// ---------- GEMM: C[M,N] = A[M,K](bf16) @ W[N,K](bf16)^T + bias ----------
// m97 structure: 128xTN tile, BK=32, 4 waves, global_load_lds width-16 staging.
// EPI: 0 = fp32 out, 1 = bf16 out with Q-part (*0.125) scale, 2 = exact-GELU bf16 out
// TN: 128 or 64
template <int EPI, int TN>
__global__ __launch_bounds__(256) void gemm_bt(const unsigned short* __restrict__ A,
                                               const unsigned short* __restrict__ Wb,
                                               const float* __restrict__ bias,
                                               void* __restrict__ Cout,
                                               int Ksz, int Nsz) {
  constexpr int BN = TN / 32;  // 16-col tiles per wave
  __shared__ alignas(16) unsigned short As[128 * 32];
  __shared__ alignas(16) unsigned short Bs[TN * 32];

  const int t = threadIdx.x;
  const int lane = t & 63;
  const int w = t >> 6;
  const int g = lane >> 4;
  const int qi = lane & 15;
  const int wr = w >> 1;
  const int wc = w & 1;
  const int m0 = blockIdx.y * 128;
  const int n0 = blockIdx.x * TN;

  f32x4 acc[4][BN];
#pragma unroll
  for (int am = 0; am < 4; am++)
#pragma unroll
    for (int bn = 0; bn < BN; bn++) acc[am][bn] = (f32x4){0.f, 0.f, 0.f, 0.f};

  const int srow = t >> 2;
  const int schk = t & 3;
  const unsigned short* Ag = A  + (size_t)(m0 + srow) * Ksz + schk * 8;
  const unsigned short* Bg = Wb + (size_t)(n0 + srow) * Ksz + schk * 8;

  for (int kt = 0; kt < Ksz; kt += 32) {
    __syncthreads();
    // LDS dest byte offset == wave-uniform base + lane*16 — required by global_load_lds
    gll16(Ag + kt,                    As + srow * 32 + schk * 8);
    gll16(Ag + (size_t)64 * Ksz + kt, As + (srow + 64) * 32 + schk * 8);
    gll16(Bg + kt,                    Bs + srow * 32 + schk * 8);
    if constexpr (TN == 128)
      gll16(Bg + (size_t)64 * Ksz + kt, Bs + (srow + 64) * 32 + schk * 8);
    __syncthreads();

    bf16x8 af[4], bfr[BN];
#pragma unroll
    for (int am = 0; am < 4; am++)
      af[am] = *(const bf16x8*)(As + (wr * 64 + am * 16 + qi) * 32 + g * 8);
#pragma unroll
    for (int bn = 0; bn < BN; bn++)
      bfr[bn] = *(const bf16x8*)(Bs + (wc * (TN / 2) + bn * 16 + qi) * 32 + g * 8);
#pragma unroll
    for (int am = 0; am < 4; am++)
#pragma unroll
      for (int bn = 0; bn < BN; bn++)
        acc[am][bn] = mfma16(af[am], bfr[bn], acc[am][bn]);
  }

  float bv[BN];
#pragma unroll
  for (int bn = 0; bn < BN; bn++)
    bv[bn] = bias[n0 + wc * (TN / 2) + bn * 16 + qi];

#pragma unroll
  for (int am = 0; am < 4; am++)
#pragma unroll
    for (int bn = 0; bn < BN; bn++)
#pragma unroll
      for (int r = 0; r < 4; r++) {
        // C/D layout: col = lane&15, row = (lane>>4)*4 + r   [m89/m91 verified]
        const int mrow = m0 + wr * 64 + am * 16 + g * 4 + r;
        const int ncol = n0 + wc * (TN / 2) + bn * 16 + qi;
        float v = acc[am][bn][r] + bv[bn];
        if constexpr (EPI == 0) {
          ((float*)Cout)[(size_t)mrow * Nsz + ncol] = v;
        } else if constexpr (EPI == 1) {
          if (ncol < DM) v *= 0.125f;  // pre-scale Q by 1/sqrt(dh)
          ((unsigned short*)Cout)[(size_t)mrow * Nsz + ncol] = f2bf(v);
        } else {
          v = 0.5f * v * (1.f + erff(v * 0.70710678118654752f));
          ((unsigned short*)Cout)[(size_t)mrow * Nsz + ncol] = f2bf(v);
        }
      }
}

// ---------- Flash attention ----------
// qkv: bf16 [B,N,3*D], Q part pre-scaled by 1/8. out: bf16 [B,N,D].
// Block = 128 threads (2 waves); each wave owns 32 q rows; KV tiles of 128.
// Swapped QK^T (mfma(K,Q)) -> softmax stats lane-local per q row.
__global__ __launch_bounds__(128) void attn_kernel(const unsigned short* __restrict__ qkv,
                                                   unsigned short* __restrict__ outp) {
  __shared__ alignas(16) unsigned short Ks[128 * 64];   // K tile, chunk-swizzled
  __shared__ alignas(16) unsigned short Vt[64 * 128];   // V^T, chunk-swizzled
  __shared__ alignas(16) unsigned short Ps[2][32 * 128];// per-wave P, chunk-swizzled

  const int t = threadIdx.x;
  const int w = t >> 6;
  const int lane = t & 63;
  const int g = lane >> 4;
  const int qi = lane & 15;
  const int bidx = blockIdx.x;
  const int qtile = bidx & 15;
  const int bh = bidx >> 4;
  const int h = bh % NH;
  const int b = bh / NH;
  const int q0 = qtile * 64 + w * 32;
  const size_t base_bn = (size_t)b * NT;

  // Q fragments (MFMA B operand in S^T = K @ Q^T): lane holds Q[q0+qt*16+qi][k-chunk g]
  bf16x8 qf[2][2];
#pragma unroll
  for (int qt = 0; qt < 2; qt++)
#pragma unroll
    for (int kk = 0; kk < 2; kk++) {
      const int qrow = q0 + qt * 16 + qi;
      qf[qt][kk] = *(const bf16x8*)(qkv + (base_bn + qrow) * TD + h * 64 + kk * 32 + g * 8);
    }

  f32x4 oacc[2][4];
#pragma unroll
  for (int qt = 0; qt < 2; qt++)
#pragma unroll
    for (int dt = 0; dt < 4; dt++) oacc[qt][dt] = (f32x4){0.f, 0.f, 0.f, 0.f};
  float mval[2] = {-__builtin_inff(), -__builtin_inff()};
  float lval[2] = {0.f, 0.f};
  unsigned short* Pw = &Ps[w][0];

  for (int kv0 = 0; kv0 < NT; kv0 += 128) {
    __syncthreads();
    // --- stage K: linear LDS dest (byte = lane*16), source chunk pre-swizzled ---
#pragma unroll
    for (int rr = 0; rr < 8; rr++) {
      const int n = rr * 16 + (t >> 3);
      const int cd = t & 7;
      const int cg = cd ^ (n & 7);
      const unsigned short* src = qkv + (base_bn + kv0 + n) * TD + DM + h * 64 + cg * 8;
      gll16(src, Ks + n * 64 + cd * 8);
    }
    // --- stage V^T: 8B coalesced loads, b128 swizzled writes (uniform bank spread) ---
    // thread covers an 8-key x 4-d block; Vt[d][chunk kb ^ (d&7)] matches read swizzle
#pragma unroll
    for (int r2 = 0; r2 < 2; r2++) {
      const int kb = t >> 3;                 // key block [0,16)
      const int d0 = r2 * 32 + (t & 7) * 4;  // d base
      u16x4 vv[8];
#pragma unroll
      for (int i = 0; i < 8; i++)
        vv[i] = *(const u16x4*)(qkv + (base_bn + kv0 + kb * 8 + i) * TD + 2 * DM + h * 64 + d0);
#pragma unroll
      for (int j = 0; j < 4; j++) {
        const int d = d0 + j;
        u16x8 w8;
#pragma unroll
        for (int i = 0; i < 8; i++) w8[i] = vv[i][j];
        *(u16x8*)((char*)Vt + d * 256 + ((kb ^ (d & 7)) * 16)) = w8;
      }
    }
    __syncthreads();

    // --- S^T = K @ Q^T : sacc[nt][qt][r] = S[q=qt*16+qi][key=nt*16+g*4+r] ---
    f32x4 sacc[8][2];
#pragma unroll
    for (int nt = 0; nt < 8; nt++)
#pragma unroll
      for (int qt = 0; qt < 2; qt++) sacc[nt][qt] = (f32x4){0.f, 0.f, 0.f, 0.f};
#pragma unroll
    for (int nt = 0; nt < 8; nt++) {
      const int n = nt * 16 + qi;
      bf16x8 kf0 = *(const bf16x8*)((const char*)Ks + n * 128 + (((0 + g) ^ (n & 7)) * 16));
      bf16x8 kf1 = *(const bf16x8*)((const char*)Ks + n * 128 + (((4 + g) ^ (n & 7)) * 16));
#pragma unroll
      for (int qt = 0; qt < 2; qt++) {
        sacc[nt][qt] = mfma16(kf0, qf[qt][0], sacc[nt][qt]);
        sacc[nt][qt] = mfma16(kf1, qf[qt][1], sacc[nt][qt]);
      }
    }

    // --- online softmax (per-lane stats for q = qt*16+qi; reduce over g via shfl) ---
#pragma unroll
    for (int qt = 0; qt < 2; qt++) {
      float mx = -__builtin_inff();
#pragma unroll
      for (int nt = 0; nt < 8; nt++)
#pragma unroll
        for (int r = 0; r < 4; r++) mx = fmaxf(mx, sacc[nt][qt][r]);
      mx = fmaxf(mx, __shfl_xor(mx, 16, 64));
      mx = fmaxf(mx, __shfl_xor(mx, 32, 64));
      const float mnew = fmaxf(mval[qt], mx);
      const float scl = __expf(mval[qt] - mnew);
      mval[qt] = mnew;
      float rsum = 0.f;
#pragma unroll
      for (int nt = 0; nt < 8; nt++)
#pragma unroll
        for (int r = 0; r < 4; r++) {
          const float p = __expf(sacc[nt][qt][r] - mnew);
          sacc[nt][qt][r] = p;
          rsum += p;
        }
      rsum += __shfl_xor(rsum, 16, 64);
      rsum += __shfl_xor(rsum, 32, 64);
      lval[qt] = lval[qt] * scl + rsum;
      // rescale O (oacc row q = qt*16 + g*4 + r; its scale lives in lane g*4+r)
#pragma unroll
      for (int r = 0; r < 4; r++) {
        const float sr = __shfl(scl, g * 4 + r, 64);
#pragma unroll
        for (int dt = 0; dt < 4; dt++) oacc[qt][dt][r] *= sr;
      }
      // write P tile (bf16) to per-wave LDS, chunk-swizzled by q-row
      const int qrow = qt * 16 + qi;
#pragma unroll
      for (int nt = 0; nt < 8; nt++) {
        u16x4 pk;
#pragma unroll
        for (int r = 0; r < 4; r++) pk[r] = f2bf(sacc[nt][qt][r]);
        const int byteoff = qrow * 256 + (((2 * nt + (g >> 1)) ^ (qrow & 7)) * 16) + (g & 1) * 8;
        *(u16x4*)((char*)Pw + byteoff) = pk;
      }
    }

    // --- O += P @ V ---
#pragma unroll
    for (int kk2 = 0; kk2 < 4; kk2++) {
      bf16x8 pf[2], vf[4];
#pragma unroll
      for (int qt = 0; qt < 2; qt++) {
        const int qrow = qt * 16 + qi;
        pf[qt] = *(const bf16x8*)((const char*)Pw + qrow * 256 + (((kk2 * 4 + g) ^ (qrow & 7)) * 16));
      }
#pragma unroll
      for (int dt = 0; dt < 4; dt++) {
        const int d = dt * 16 + qi;
        vf[dt] = *(const bf16x8*)((const char*)Vt + d * 256 + (((kk2 * 4 + g) ^ (d & 7)) * 16));
      }
#pragma unroll
      for (int qt = 0; qt < 2; qt++)
#pragma unroll
        for (int dt = 0; dt < 4; dt++)
          oacc[qt][dt] = mfma16(pf[qt], vf[dt], oacc[qt][dt]);
    }
  }

  // --- finalize: O / l, write bf16 ---
#pragma unroll
  for (int qt = 0; qt < 2; qt++) {
    const float linv = 1.f / lval[qt];
#pragma unroll
    for (int r = 0; r < 4; r++) {
      const float lr = __shfl(linv, g * 4 + r, 64);
      const int qrow = q0 + qt * 16 + g * 4 + r;
#pragma unroll
      for (int dt = 0; dt < 4; dt++) {
        const float v = oacc[qt][dt][r] * lr;
        outp[(base_bn + qrow) * DM + h * 64 + dt * 16 + qi] = f2bf(v);
      }
    }
  }
}

// ---------- host ----------
extern "C" void kernel_launch(void* const* d_in, const int* in_sizes, int n_in,
                              void* d_out, int out_size, void* d_ws, size_t ws_size,
                              hipStream_t stream) {
  const float* x_in = (const float*)d_in[0];
  const float* Wqkv = (const float*)d_in[1];
  const float* bqkv = (const float*)d_in[2];
  const float* Wo   = (const float*)d_in[3];
  const float* bo   = (const float*)d_in[4];
  const float* ln1g = (const float*)d_in[5];
  const float* ln1b = (const float*)d_in[6];
  const float* ln2g = (const float*)d_in[7];
  const float* ln2b = (const float*)d_in[8];
  const float* W1   = (const float*)d_in[9];
  const float* b1   = (const float*)d_in[10];
  const float* W2   = (const float*)d_in[11];
  const float* b2   = (const float*)d_in[12];
  float* outp = (float*)d_out;

  char* ws = (char*)d_ws;
  size_t off = 0;
  auto alloc = [&](size_t bytes) {
    void* p = ws + off;
    off += (bytes + 255) & ~(size_t)255;
    return p;
  };
  // per-layer bf16 weight slots (reused across layers) — keeps ws ~96 MB
  unsigned short* wq_l = (unsigned short*)alloc((size_t)TD * DM * 2);
  unsigned short* wo_l = (unsigned short*)alloc((size_t)DM * DM * 2);
  unsigned short* w1_l = (unsigned short*)alloc((size_t)FFD * DM * 2);
  unsigned short* w2_l = (unsigned short*)alloc((size_t)DM * FFD * 2);
  unsigned short* src_bf  = (unsigned short*)alloc((size_t)MM * DM * 2);
  unsigned short* qkv_bf  = (unsigned short*)alloc((size_t)MM * TD * 2);
  unsigned short* attn_bf = (unsigned short*)alloc((size_t)MM * DM * 2);
  unsigned short* h_bf    = (unsigned short*)alloc((size_t)MM * FFD * 2);
  float* abuf             = (float*)alloc((size_t)MM * DM * 4);
  float* x_f32            = (float*)alloc((size_t)MM * DM * 4);

  for (int l = 0; l < LAYERS; l++) {
    const float* xcur = (l == 0) ? x_in : x_f32;
    // weight convert fp32 -> bf16 for this layer
    cvt_kernel<<<512, 256, 0, stream>>>((const f32x4*)(Wqkv + (size_t)l * TD * DM),
                                        (u16x4*)wq_l, TD * DM / 4);
    cvt_kernel<<<512, 256, 0, stream>>>((const f32x4*)(Wo + (size_t)l * DM * DM),
                                        (u16x4*)wo_l, DM * DM / 4);
    cvt_kernel<<<512, 256, 0, stream>>>((const f32x4*)(W1 + (size_t)l * FFD * DM),
                                        (u16x4*)w1_l, FFD * DM / 4);
    cvt_kernel<<<512, 256, 0, stream>>>((const f32x4*)(W2 + (size_t)l * DM * FFD),
                                        (u16x4*)w2_l, DM * FFD / 4);

    // src = LN1(x) -> bf16
    ln_kernel<<<1024, 256, 0, stream>>>(xcur, nullptr, ln1g + l * DM, ln1b + l * DM,
                                        nullptr, src_bf);
    // qkv = src @ Wqkv^T + bqkv (Q pre-scaled by 1/8)
    gemm_bt<1, 128><<<dim3(TD / 128, MM / 128), 256, 0, stream>>>(
        src_bf, wq_l, bqkv + l * TD, qkv_bf, DM, TD);
    // flash attention
    attn_kernel<<<BB * NH * (NT / 64), 128, 0, stream>>>(qkv_bf, attn_bf);
    // a = attn @ Wo^T + bo (fp32)
    gemm_bt<0, 64><<<dim3(DM / 64, MM / 128), 256, 0, stream>>>(
        attn_bf, wo_l, bo + l * DM, abuf, DM, DM);
    // x = LN1(x + a) -> fp32 + bf16
    ln_kernel<<<1024, 256, 0, stream>>>(xcur, abuf, ln1g + l * DM, ln1b + l * DM,
                                        x_f32, src_bf);
    // h = gelu(x @ W1^T + b1) -> bf16
    gemm_bt<2, 128><<<dim3(FFD / 128, MM / 128), 256, 0, stream>>>(
        src_bf, w1_l, b1 + l * FFD, h_bf, DM, FFD);
    // a = h @ W2^T + b2 (fp32)
    gemm_bt<0, 64><<<dim3(DM / 64, MM / 128), 256, 0, stream>>>(
        h_bf, w2_l, b2 + l * DM, abuf, FFD, DM);
    // x = LN2(x + a)
    ln_kernel<<<1024, 256, 0, stream>>>(x_f32, abuf, ln2g + l * DM, ln2b + l * DM,
                                        (l == LAYERS - 1) ? outp : x_f32, nullptr);
  }
  (void)in_sizes; (void)n_in; (void)out_size; (void)ws_size;
}

// Round 4
// 1394.540 us; speedup vs baseline: 1.1663x; 1.1663x over previous
//
#include <hip/hip_runtime.h>
#include <math.h>

#define DEV __device__ __forceinline__

typedef __attribute__((ext_vector_type(4))) float f32x4;
typedef __attribute__((ext_vector_type(8))) __bf16 bf16x8;
typedef __attribute__((ext_vector_type(4))) unsigned short u16x4;
typedef __attribute__((ext_vector_type(8))) unsigned short u16x8;

// ---------- constants ----------
enum {
  LAYERS = 6, NH = 12, DM = 768, FFD = 3072, BB = 4, NT = 1024,
  MM = BB * NT,          // 4096 token rows
  TD = 3 * DM            // 2304
};

// ---------- helpers ----------
DEV unsigned short f2bf(float f) {
  union { float f; unsigned u; } c; c.f = f;
  unsigned u = c.u;
  return (unsigned short)((u + 0x7fffu + ((u >> 16) & 1u)) >> 16);
}

DEV void gll16(const void* gsrc, void* ldst) {
  __builtin_amdgcn_global_load_lds(
      (const __attribute__((address_space(1))) unsigned int*)gsrc,
      (__attribute__((address_space(3))) unsigned int*)ldst, 16, 0, 0);
}

DEV f32x4 mfma16(bf16x8 a, bf16x8 b, f32x4 c) {
  return __builtin_amdgcn_mfma_f32_16x16x32_bf16(a, b, c, 0, 0, 0);
}

// bijective XCD-aware remap (m204): cluster contiguous tile ids per XCD
DEV int xcd_remap(int id, int nwg) {
  const int q = nwg >> 3, r = nwg & 7;
  const int xcd = id & 7, j = id >> 3;
  return (xcd < r ? xcd * (q + 1) : r * (q + 1) + (xcd - r) * q) + j;
}

// ---------- fused per-layer fp32 -> bf16 weight convert (4 tensors) ----------
__global__ __launch_bounds__(256) void cvt4_kernel(
    const f32x4* __restrict__ i0, u16x4* __restrict__ o0, int c0,
    const f32x4* __restrict__ i1, u16x4* __restrict__ o1, int c1,
    const f32x4* __restrict__ i2, u16x4* __restrict__ o2, int c2,
    const f32x4* __restrict__ i3, u16x4* __restrict__ o3, int c3) {
  int i = blockIdx.x * 256 + threadIdx.x;
  const int stride = gridDim.x * 256;
  const int total = c0 + c1 + c2 + c3;
  for (; i < total; i += stride) {
    const f32x4* src; u16x4* dst; int k = i;
    if (k < c0) { src = i0; dst = o0; }
    else {
      k -= c0;
      if (k < c1) { src = i1; dst = o1; }
      else {
        k -= c1;
        if (k < c2) { src = i2; dst = o2; }
        else { k -= c2; src = i3; dst = o3; }
      }
    }
    f32x4 v = src[k];
    u16x4 o;
    o[0] = f2bf(v[0]); o[1] = f2bf(v[1]); o[2] = f2bf(v[2]); o[3] = f2bf(v[3]);
    dst[k] = o;
  }
}

// ---------- LayerNorm (fused residual adds), wave per row ----------
// x = LN(xin [+ ain] [+ ain2]); outputs fp32 (xout) and/or bf16 (bfout)
__global__ __launch_bounds__(256) void ln_kernel(const float* __restrict__ xin,
                                                 const float* __restrict__ ain,
                                                 const float* __restrict__ ain2,
                                                 const float* __restrict__ gam,
                                                 const float* __restrict__ bet,
                                                 float* __restrict__ xout,
                                                 unsigned short* __restrict__ bfout) {
  const int row  = blockIdx.x * 4 + (threadIdx.x >> 6);
  const int lane = threadIdx.x & 63;
  const f32x4* xr = (const f32x4*)(xin + (size_t)row * DM);
  f32x4 v[3];
#pragma unroll
  for (int p = 0; p < 3; p++) v[p] = xr[lane + 64 * p];
  if (ain) {
    const f32x4* ar = (const f32x4*)(ain + (size_t)row * DM);
#pragma unroll
    for (int p = 0; p < 3; p++) v[p] += ar[lane + 64 * p];
  }
  if (ain2) {
    const f32x4* ar = (const f32x4*)(ain2 + (size_t)row * DM);
#pragma unroll
    for (int p = 0; p < 3; p++) v[p] += ar[lane + 64 * p];
  }
  float s = 0.f, sq = 0.f;
#pragma unroll
  for (int p = 0; p < 3; p++)
#pragma unroll
    for (int j = 0; j < 4; j++) { float f = v[p][j]; s += f; sq += f * f; }
#pragma unroll
  for (int o = 1; o < 64; o <<= 1) {
    s  += __shfl_xor(s, o, 64);
    sq += __shfl_xor(sq, o, 64);
  }
  const float mean = s * (1.0f / DM);
  const float var  = sq * (1.0f / DM) - mean * mean;
  const float rstd = rsqrtf(var + 1e-5f);
  const f32x4* gr = (const f32x4*)gam;
  const f32x4* br = (const f32x4*)bet;
#pragma unroll
  for (int p = 0; p < 3; p++) {
    f32x4 gv = gr[lane + 64 * p];
    f32x4 bv = br[lane + 64 * p];
    f32x4 o = (v[p] - mean) * rstd * gv + bv;
    if (xout) ((f32x4*)(xout + (size_t)row * DM))[lane + 64 * p] = o;
    if (bfout) {
      u16x4 h;
      h[0] = f2bf(o[0]); h[1] = f2bf(o[1]); h[2] = f2bf(o[2]); h[3] = f2bf(o[3]);
      ((u16x4*)(bfout + (size_t)row * DM))[lane + 64 * p] = h;
    }
  }
}

// ---------- GEMM: C[M,N] = A[M,K](bf16) @ W[N,K](bf16)^T + bias ----------
// m97 structure: 128xTN tile, BK=32, 4 waves, global_load_lds width-16 staging.
// gridDim.z = split-K factor (EPI==0 only): slice tz writes fp32 partials to
// Cout + tz*M*N; bias added only in slice 0. XCD-aware tile remap throughout.
// EPI: 0 = fp32 out, 1 = bf16 out with Q-part (*0.125) scale, 2 = exact-GELU bf16 out
template <int EPI, int TN>
__global__ __launch_bounds__(256) void gemm_bt(const unsigned short* __restrict__ A,
                                               const unsigned short* __restrict__ Wb,
                                               const float* __restrict__ bias,
                                               void* __restrict__ Cout,
                                               int Ksz, int Nsz) {
  constexpr int BN = TN / 32;  // 16-col tiles per wave
  __shared__ alignas(16) unsigned short As[128 * 32];
  __shared__ alignas(16) unsigned short Bs[TN * 32];

  const int gx = gridDim.x, gy = gridDim.y, gz = gridDim.z;
  int id = blockIdx.x + gx * (blockIdx.y + gy * blockIdx.z);
  id = xcd_remap(id, gx * gy * gz);
  const int tz = id / (gx * gy);
  const int rem = id - tz * (gx * gy);
  const int ty = rem / gx;
  const int tx = rem - ty * gx;

  const int t = threadIdx.x;
  const int lane = t & 63;
  const int w = t >> 6;
  const int g = lane >> 4;
  const int qi = lane & 15;
  const int wr = w >> 1;
  const int wc = w & 1;
  const int m0 = ty * 128;
  const int n0 = tx * TN;
  const int ksz_per = Ksz / gz;
  const int k_begin = tz * ksz_per;
  const int k_end = k_begin + ksz_per;

  f32x4 acc[4][BN];
#pragma unroll
  for (int am = 0; am < 4; am++)
#pragma unroll
    for (int bn = 0; bn < BN; bn++) acc[am][bn] = (f32x4){0.f, 0.f, 0.f, 0.f};

  const int srow = t >> 2;
  const int schk = t & 3;
  const unsigned short* Ag = A  + (size_t)(m0 + srow) * Ksz + schk * 8;
  const unsigned short* Bg = Wb + (size_t)(n0 + srow) * Ksz + schk * 8;

  for (int kt = k_begin; kt < k_end; kt += 32) {
    __syncthreads();
    // LDS dest byte offset == wave-uniform base + lane*16 — required by global_load_lds
    gll16(Ag + kt,                    As + srow * 32 + schk * 8);
    gll16(Ag + (size_t)64 * Ksz + kt, As + (srow + 64) * 32 + schk * 8);
    gll16(Bg + kt,                    Bs + srow * 32 + schk * 8);
    if constexpr (TN == 128)
      gll16(Bg + (size_t)64 * Ksz + kt, Bs + (srow + 64) * 32 + schk * 8);
    __syncthreads();

    bf16x8 af[4], bfr[BN];
#pragma unroll
    for (int am = 0; am < 4; am++)
      af[am] = *(const bf16x8*)(As + (wr * 64 + am * 16 + qi) * 32 + g * 8);
#pragma unroll
    for (int bn = 0; bn < BN; bn++)
      bfr[bn] = *(const bf16x8*)(Bs + (wc * (TN / 2) + bn * 16 + qi) * 32 + g * 8);
#pragma unroll
    for (int am = 0; am < 4; am++)
#pragma unroll
      for (int bn = 0; bn < BN; bn++)
        acc[am][bn] = mfma16(af[am], bfr[bn], acc[am][bn]);
  }

  float bv[BN];
#pragma unroll
  for (int bn = 0; bn < BN; bn++)
    bv[bn] = (tz == 0) ? bias[n0 + wc * (TN / 2) + bn * 16 + qi] : 0.f;

  // fp32 split-K slice base (EPI==0); M = gy*128
  float* Cf = (float*)Cout + (size_t)tz * ((size_t)gy * 128) * Nsz;

#pragma unroll
  for (int am = 0; am < 4; am++)
#pragma unroll
    for (int bn = 0; bn < BN; bn++)
#pragma unroll
      for (int r = 0; r < 4; r++) {
        // C/D layout: col = lane&15, row = (lane>>4)*4 + r   [m89/m91 verified]
        const int mrow = m0 + wr * 64 + am * 16 + g * 4 + r;
        const int ncol = n0 + wc * (TN / 2) + bn * 16 + qi;
        float v = acc[am][bn][r] + bv[bn];
        if constexpr (EPI == 0) {
          Cf[(size_t)mrow * Nsz + ncol] = v;
        } else if constexpr (EPI == 1) {
          if (ncol < DM) v *= 0.125f;  // pre-scale Q by 1/sqrt(dh)
          ((unsigned short*)Cout)[(size_t)mrow * Nsz + ncol] = f2bf(v);
        } else {
          v = 0.5f * v * (1.f + erff(v * 0.70710678118654752f));
          ((unsigned short*)Cout)[(size_t)mrow * Nsz + ncol] = f2bf(v);
        }
      }
}

// ---------- Flash attention ----------
// qkv: bf16 [B,N,3*D], Q part pre-scaled by 1/8. out: bf16 [B,N,D].
// Block = 128 threads (2 waves); each wave owns 32 q rows; KV tiles of 128.
// Swapped QK^T (mfma(K,Q)) -> softmax stats lane-local per q row.
__global__ __launch_bounds__(128) void attn_kernel(const unsigned short* __restrict__ qkv,
                                                   unsigned short* __restrict__ outp) {
  __shared__ alignas(16) unsigned short Ks[128 * 64];   // K tile, chunk-swizzled
  __shared__ alignas(16) unsigned short Vt[64 * 128];   // V^T, chunk-swizzled
  __shared__ alignas(16) unsigned short Ps[2][32 * 128];// per-wave P, chunk-swizzled

  const int t = threadIdx.x;
  const int w = t >> 6;
  const int lane = t & 63;
  const int g = lane >> 4;
  const int qi = lane & 15;
  // XCD remap: 16 q-tiles of one (b,h) share K/V -> keep them on one XCD's L2
  const int bidx = xcd_remap(blockIdx.x, gridDim.x);
  const int qtile = bidx & 15;
  const int bh = bidx >> 4;
  const int h = bh % NH;
  const int b = bh / NH;
  const int q0 = qtile * 64 + w * 32;
  const size_t base_bn = (size_t)b * NT;

  // Q fragments (MFMA B operand in S^T = K @ Q^T): lane holds Q[q0+qt*16+qi][k-chunk g]
  bf16x8 qf[2][2];
#pragma unroll
  for (int qt = 0; qt < 2; qt++)
#pragma unroll
    for (int kk = 0; kk < 2; kk++) {
      const int qrow = q0 + qt * 16 + qi;
      qf[qt][kk] = *(const bf16x8*)(qkv + (base_bn + qrow) * TD + h * 64 + kk * 32 + g * 8);
    }

  f32x4 oacc[2][4];
#pragma unroll
  for (int qt = 0; qt < 2; qt++)
#pragma unroll
    for (int dt = 0; dt < 4; dt++) oacc[qt][dt] = (f32x4){0.f, 0.f, 0.f, 0.f};
  float mval[2] = {-__builtin_inff(), -__builtin_inff()};
  float lval[2] = {0.f, 0.f};
  unsigned short* Pw = &Ps[w][0];

  for (int kv0 = 0; kv0 < NT; kv0 += 128) {
    __syncthreads();
    // --- stage K: linear LDS dest (byte = lane*16), source chunk pre-swizzled ---
#pragma unroll
    for (int rr = 0; rr < 8; rr++) {
      const int n = rr * 16 + (t >> 3);
      const int cd = t & 7;
      const int cg = cd ^ (n & 7);
      const unsigned short* src = qkv + (base_bn + kv0 + n) * TD + DM + h * 64 + cg * 8;
      gll16(src, Ks + n * 64 + cd * 8);
    }
    // --- stage V^T: 8B coalesced loads, b128 swizzled writes (uniform bank spread) ---
    // thread covers an 8-key x 4-d block; Vt[d][chunk kb ^ (d&7)] matches read swizzle
#pragma unroll
    for (int r2 = 0; r2 < 2; r2++) {
      const int kb = t >> 3;                 // key block [0,16)
      const int d0 = r2 * 32 + (t & 7) * 4;  // d base
      u16x4 vv[8];
#pragma unroll
      for (int i = 0; i < 8; i++)
        vv[i] = *(const u16x4*)(qkv + (base_bn + kv0 + kb * 8 + i) * TD + 2 * DM + h * 64 + d0);
#pragma unroll
      for (int j = 0; j < 4; j++) {
        const int d = d0 + j;
        u16x8 w8;
#pragma unroll
        for (int i = 0; i < 8; i++) w8[i] = vv[i][j];
        *(u16x8*)((char*)Vt + d * 256 + ((kb ^ (d & 7)) * 16)) = w8;
      }
    }
    __syncthreads();

    // --- S^T = K @ Q^T : sacc[nt][qt][r] = S[q=qt*16+qi][key=nt*16+g*4+r] ---
    f32x4 sacc[8][2];
#pragma unroll
    for (int nt = 0; nt < 8; nt++)
#pragma unroll
      for (int qt = 0; qt < 2; qt++) sacc[nt][qt] = (f32x4){0.f, 0.f, 0.f, 0.f};
#pragma unroll
    for (int nt = 0; nt < 8; nt++) {
      const int n = nt * 16 + qi;
      bf16x8 kf0 = *(const bf16x8*)((const char*)Ks + n * 128 + (((0 + g) ^ (n & 7)) * 16));
      bf16x8 kf1 = *(const bf16x8*)((const char*)Ks + n * 128 + (((4 + g) ^ (n & 7)) * 16));
#pragma unroll
      for (int qt = 0; qt < 2; qt++) {
        sacc[nt][qt] = mfma16(kf0, qf[qt][0], sacc[nt][qt]);
        sacc[nt][qt] = mfma16(kf1, qf[qt][1], sacc[nt][qt]);
      }
    }

    // --- online softmax (per-lane stats for q = qt*16+qi; reduce over g via shfl) ---
#pragma unroll
    for (int qt = 0; qt < 2; qt++) {
      float mx = -__builtin_inff();
#pragma unroll
      for (int nt = 0; nt < 8; nt++)
#pragma unroll
        for (int r = 0; r < 4; r++) mx = fmaxf(mx, sacc[nt][qt][r]);
      mx = fmaxf(mx, __shfl_xor(mx, 16, 64));
      mx = fmaxf(mx, __shfl_xor(mx, 32, 64));
      const float mnew = fmaxf(mval[qt], mx);
      const float scl = __expf(mval[qt] - mnew);
      mval[qt] = mnew;
      float rsum = 0.f;
#pragma unroll
      for (int nt = 0; nt < 8; nt++)
#pragma unroll
        for (int r = 0; r < 4; r++) {
          const float p = __expf(sacc[nt][qt][r] - mnew);
          sacc[nt][qt][r] = p;
          rsum += p;
        }
      rsum += __shfl_xor(rsum, 16, 64);
      rsum += __shfl_xor(rsum, 32, 64);
      lval[qt] = lval[qt] * scl + rsum;
      // rescale O (oacc row q = qt*16 + g*4 + r; its scale lives in lane g*4+r)
#pragma unroll
      for (int r = 0; r < 4; r++) {
        const float sr = __shfl(scl, g * 4 + r, 64);
#pragma unroll
        for (int dt = 0; dt < 4; dt++) oacc[qt][dt][r] *= sr;
      }
      // write P tile (bf16) to per-wave LDS, chunk-swizzled by q-row
      const int qrow = qt * 16 + qi;
#pragma unroll
      for (int nt = 0; nt < 8; nt++) {
        u16x4 pk;
#pragma unroll
        for (int r = 0; r < 4; r++) pk[r] = f2bf(sacc[nt][qt][r]);
        const int byteoff = qrow * 256 + (((2 * nt + (g >> 1)) ^ (qrow & 7)) * 16) + (g & 1) * 8;
        *(u16x4*)((char*)Pw + byteoff) = pk;
      }
    }

    // --- O += P @ V ---
#pragma unroll
    for (int kk2 = 0; kk2 < 4; kk2++) {
      bf16x8 pf[2], vf[4];
#pragma unroll
      for (int qt = 0; qt < 2; qt++) {
        const int qrow = qt * 16 + qi;
        pf[qt] = *(const bf16x8*)((const char*)Pw + qrow * 256 + (((kk2 * 4 + g) ^ (qrow & 7)) * 16));
      }
#pragma unroll
      for (int dt = 0; dt < 4; dt++) {
        const int d = dt * 16 + qi;
        vf[dt] = *(const bf16x8*)((const char*)Vt + d * 256 + (((kk2 * 4 + g) ^ (d & 7)) * 16));
      }
#pragma unroll
      for (int qt = 0; qt < 2; qt++)
#pragma unroll
        for (int dt = 0; dt < 4; dt++)
          oacc[qt][dt] = mfma16(pf[qt], vf[dt], oacc[qt][dt]);
    }
  }

  // --- finalize: O / l, write bf16 ---
#pragma unroll
  for (int qt = 0; qt < 2; qt++) {
    const float linv = 1.f / lval[qt];
#pragma unroll
    for (int r = 0; r < 4; r++) {
      const float lr = __shfl(linv, g * 4 + r, 64);
      const int qrow = q0 + qt * 16 + g * 4 + r;
#pragma unroll
      for (int dt = 0; dt < 4; dt++) {
        const float v = oacc[qt][dt][r] * lr;
        outp[(base_bn + qrow) * DM + h * 64 + dt * 16 + qi] = f2bf(v);
      }
    }
  }
}

// ---------- host ----------
extern "C" void kernel_launch(void* const* d_in, const int* in_sizes, int n_in,
                              void* d_out, int out_size, void* d_ws, size_t ws_size,
                              hipStream_t stream) {
  const float* x_in = (const float*)d_in[0];
  const float* Wqkv = (const float*)d_in[1];
  const float* bqkv = (const float*)d_in[2];
  const float* Wo   = (const float*)d_in[3];
  const float* bo   = (const float*)d_in[4];
  const float* ln1g = (const float*)d_in[5];
  const float* ln1b = (const float*)d_in[6];
  const float* ln2g = (const float*)d_in[7];
  const float* ln2b = (const float*)d_in[8];
  const float* W1   = (const float*)d_in[9];
  const float* b1   = (const float*)d_in[10];
  const float* W2   = (const float*)d_in[11];
  const float* b2   = (const float*)d_in[12];
  float* outp = (float*)d_out;

  char* ws = (char*)d_ws;
  size_t off = 0;
  auto alloc = [&](size_t bytes) {
    void* p = ws + off;
    off += (bytes + 255) & ~(size_t)255;
    return p;
  };
  // per-layer bf16 weight slots (reused across layers)
  unsigned short* wq_l = (unsigned short*)alloc((size_t)TD * DM * 2);
  unsigned short* wo_l = (unsigned short*)alloc((size_t)DM * DM * 2);
  unsigned short* w1_l = (unsigned short*)alloc((size_t)FFD * DM * 2);
  unsigned short* w2_l = (unsigned short*)alloc((size_t)DM * FFD * 2);
  unsigned short* src_bf  = (unsigned short*)alloc((size_t)MM * DM * 2);
  unsigned short* qkv_bf  = (unsigned short*)alloc((size_t)MM * TD * 2);
  unsigned short* attn_bf = (unsigned short*)alloc((size_t)MM * DM * 2);
  unsigned short* h_bf    = (unsigned short*)alloc((size_t)MM * FFD * 2);
  float* abuf             = (float*)alloc((size_t)2 * MM * DM * 4);  // 2 split-K slices
  float* x_f32            = (float*)alloc((size_t)MM * DM * 4);
  float* abuf1 = abuf + (size_t)MM * DM;

  for (int l = 0; l < LAYERS; l++) {
    const float* xcur = (l == 0) ? x_in : x_f32;
    // fused weight convert fp32 -> bf16 for this layer
    cvt4_kernel<<<1024, 256, 0, stream>>>(
        (const f32x4*)(Wqkv + (size_t)l * TD * DM), (u16x4*)wq_l, TD * DM / 4,
        (const f32x4*)(Wo   + (size_t)l * DM * DM), (u16x4*)wo_l, DM * DM / 4,
        (const f32x4*)(W1   + (size_t)l * FFD * DM), (u16x4*)w1_l, FFD * DM / 4,
        (const f32x4*)(W2   + (size_t)l * DM * FFD), (u16x4*)w2_l, DM * FFD / 4);

    // src = LN1(x) -> bf16
    ln_kernel<<<1024, 256, 0, stream>>>(xcur, nullptr, nullptr,
                                        ln1g + l * DM, ln1b + l * DM,
                                        nullptr, src_bf);
    // qkv = src @ Wqkv^T + bqkv (Q pre-scaled by 1/8)
    gemm_bt<1, 128><<<dim3(TD / 128, MM / 128), 256, 0, stream>>>(
        src_bf, wq_l, bqkv + l * TD, qkv_bf, DM, TD);
    // flash attention
    attn_kernel<<<BB * NH * (NT / 64), 128, 0, stream>>>(qkv_bf, attn_bf);
    // a = attn @ Wo^T + bo (fp32, split-K=2 -> abuf slices)
    gemm_bt<0, 64><<<dim3(DM / 64, MM / 128, 2), 256, 0, stream>>>(
        attn_bf, wo_l, bo + l * DM, abuf, DM, DM);
    // x = LN1(x + a0 + a1) -> fp32 + bf16
    ln_kernel<<<1024, 256, 0, stream>>>(xcur, abuf, abuf1,
                                        ln1g + l * DM, ln1b + l * DM,
                                        x_f32, src_bf);
    // h = gelu(x @ W1^T + b1) -> bf16
    gemm_bt<2, 128><<<dim3(FFD / 128, MM / 128), 256, 0, stream>>>(
        src_bf, w1_l, b1 + l * FFD, h_bf, DM, FFD);
    // a = h @ W2^T + b2 (fp32, split-K=2 -> abuf slices)
    gemm_bt<0, 64><<<dim3(DM / 64, MM / 128, 2), 256, 0, stream>>>(
        h_bf, w2_l, b2 + l * DM, abuf, FFD, DM);
    // x = LN2(x + a0 + a1)
    ln_kernel<<<1024, 256, 0, stream>>>(x_f32, abuf, abuf1,
                                        ln2g + l * DM, ln2b + l * DM,
                                        (l == LAYERS - 1) ? outp : x_f32, nullptr);
  }
  (void)in_sizes; (void)n_in; (void)out_size; (void)ws_size;
}